// Round 3
// baseline (611.751 us; speedup 1.0000x reference)
//
#include <hip/hip_runtime.h>
#include <hip/hip_bf16.h>

#define B_ 2
#define CIN 64
#define HH 96
#define WW 96
#define NC 32
#define HO 94
#define WO 94
#define N_ 8836
#define NPAD 8896
#define NCHUNK 139
#define SPLITN 8
#define PW 98
#define EPSV 1e-5f
#define SLOPEV 0.01f

typedef __attribute__((ext_vector_type(8))) short short8;
typedef __attribute__((ext_vector_type(4))) float f32x4;

static_assert(NPAD == NCHUNK * 64, "pad");

__device__ __forceinline__ short bf16s(float f) {
  unsigned u = __float_as_uint(f);
  unsigned r = (u + 0x7fffu + ((u >> 16) & 1u)) >> 16;
  return (short)r;
}

// ---------------- pack conv weights: wpk[ic][oc][9] = w[oc][ic][9]*bn_scale; bfold ----------------
__global__ __launch_bounds__(256) void pack_w(
    const float* __restrict__ w, const float* __restrict__ bias,
    const float* __restrict__ g, const float* __restrict__ be,
    const float* __restrict__ m, const float* __restrict__ v,
    float* __restrict__ wpk, float* __restrict__ bfold) {
  int idx = blockIdx.x * blockDim.x + threadIdx.x;
  if (idx < CIN * NC * 9) {
    int ic = idx / (NC * 9);
    int r = idx - ic * (NC * 9);
    int oc = r / 9, k = r - oc * 9;
    float s = g[oc] * rsqrtf(v[oc] + EPSV);
    wpk[idx] = w[((size_t)oc * CIN + ic) * 9 + k] * s;
  }
  if (idx < NC) {
    float s = g[idx] * rsqrtf(v[idx] + EPSV);
    bfold[idx] = (bias[idx] - m[idx]) * s + be[idx];
  }
}

// ---------------- conv branches: each thread = 1 pixel x 16 oc ----------------
__global__ __launch_bounds__(256) void conv_brn(
    const float* __restrict__ x, const float* __restrict__ wpk,
    const float* __restrict__ bfold,
    __hip_bfloat16* __restrict__ ohi, __hip_bfloat16* __restrict__ olo) {
  int n = blockIdx.x * 256 + threadIdx.x;
  int ocb = blockIdx.y * 16, b = blockIdx.z;
  if (n >= N_) return;
  int oh = n / WO, ow = n - oh * WO;
  const float* xb = x + (size_t)b * CIN * HH * WW + oh * WW + ow;
  float acc[16];
#pragma unroll
  for (int o = 0; o < 16; ++o) acc[o] = 0.f;
  for (int ic = 0; ic < CIN; ++ic) {
    const float* xr = xb + ic * HH * WW;
    float xv[9];
#pragma unroll
    for (int r = 0; r < 3; ++r)
#pragma unroll
      for (int cc = 0; cc < 3; ++cc) xv[r * 3 + cc] = xr[r * WW + cc];
    const float* wic = wpk + ((size_t)ic * NC + ocb) * 9;
#pragma unroll
    for (int o = 0; o < 16; ++o) {
      const float* wp = wic + o * 9;
#pragma unroll
      for (int k = 0; k < 9; ++k) acc[o] += xv[k] * wp[k];
    }
  }
  size_t orow = ((size_t)b * NPAD + n) * NC + ocb;
#pragma unroll
  for (int o = 0; o < 16; ++o) {
    float y = acc[o] + bfold[ocb + o];
    y = y > 0.f ? y : SLOPEV * y;
    __hip_bfloat16 h = __float2bfloat16(y);
    ohi[orow + o] = h;
    if (olo) olo[orow + o] = __float2bfloat16(y - __bfloat162float(h));
  }
}

// ---------------- stats pass: per-lane online (mx, dn) over an n-slice ----------------
__global__ __launch_bounds__(256) void attn_stats(
    const __hip_bfloat16* __restrict__ qh, const __hip_bfloat16* __restrict__ ql,
    const __hip_bfloat16* __restrict__ kh_, const __hip_bfloat16* __restrict__ kl,
    float* __restrict__ pmx, float* __restrict__ pdn) {
  int s = blockIdx.y, b = blockIdx.z;
  int wave = threadIdx.x >> 6, lane = threadIdx.x & 63;
  int g = lane >> 4, l16 = lane & 15;
  int m16 = blockIdx.x * 64 + wave * 16;
  size_t arow = ((size_t)b * NPAD + m16 + l16) * NC + g * 8;
  short8 akh = *(const short8*)((const short*)kh_ + arow);
  short8 akl = *(const short8*)((const short*)kl + arow);
  const short* qhb = (const short*)qh + (size_t)b * NPAD * NC + g * 8;
  const short* qlb = (const short*)ql + (size_t)b * NPAD * NC + g * 8;
  float mx[4] = {-1e30f, -1e30f, -1e30f, -1e30f};
  float dn[4] = {0.f, 0.f, 0.f, 0.f};
  for (int c = s; c < NCHUNK; c += SPLITN) {
    f32x4 T[4];
#pragma unroll
    for (int nt = 0; nt < 4; ++nt) {
      int n = c * 64 + nt * 16 + l16;
      short8 bh = *(const short8*)(qhb + (size_t)n * NC);
      short8 bl = *(const short8*)(qlb + (size_t)n * NC);
      f32x4 t = __builtin_amdgcn_mfma_f32_16x16x32_bf16(akh, bh, (f32x4){0.f, 0.f, 0.f, 0.f}, 0, 0, 0);
      t = __builtin_amdgcn_mfma_f32_16x16x32_bf16(akh, bl, t, 0, 0, 0);
      t = __builtin_amdgcn_mfma_f32_16x16x32_bf16(akl, bh, t, 0, 0, 0);
      T[nt] = t;
    }
    if (c == NCHUNK - 1) {
#pragma unroll
      for (int nt = 0; nt < 4; ++nt)
        if (c * 64 + nt * 16 + l16 >= N_)
          T[nt] = (f32x4){-1e30f, -1e30f, -1e30f, -1e30f};
    }
#pragma unroll
    for (int r = 0; r < 4; ++r) {
      float cm = fmaxf(fmaxf(T[0][r], T[1][r]), fmaxf(T[2][r], T[3][r]));
      float nm = fmaxf(mx[r], cm);
      float cs = __expf(T[0][r] - nm) + __expf(T[1][r] - nm) +
                 __expf(T[2][r] - nm) + __expf(T[3][r] - nm);
      dn[r] = dn[r] * __expf(mx[r] - nm) + cs;
      mx[r] = nm;
    }
  }
#pragma unroll
  for (int r = 0; r < 4; ++r) {
#pragma unroll
    for (int off = 1; off < 16; off <<= 1) {
      float omx = __shfl_xor(mx[r], off);
      float odn = __shfl_xor(dn[r], off);
      float nm = fmaxf(mx[r], omx);
      dn[r] = dn[r] * __expf(mx[r] - nm) + odn * __expf(omx - nm);
      mx[r] = nm;
    }
    if (l16 == 0) {
      size_t mi = ((size_t)s * B_ + b) * NPAD + m16 + 4 * g + r;
      pmx[mi] = mx[r];
      pdn[mi] = dn[r];
    }
  }
}

// ---------------- merge the partial (mx, dn) into mx and 1/dn ----------------
__global__ __launch_bounds__(256) void combine_stats(
    const float* __restrict__ pmx, const float* __restrict__ pdn,
    float* __restrict__ mxo, float* __restrict__ rdn) {
  int idx = blockIdx.x * blockDim.x + threadIdx.x;
  if (idx >= B_ * NPAD) return;
  int b = idx / NPAD, m = idx - b * NPAD;
  float pm[SPLITN];
  float mx = -1e30f;
#pragma unroll
  for (int s = 0; s < SPLITN; ++s) {
    pm[s] = pmx[((size_t)s * B_ + b) * NPAD + m];
    mx = fmaxf(mx, pm[s]);
  }
  float dn = 0.f;
#pragma unroll
  for (int s = 0; s < SPLITN; ++s)
    dn += pdn[((size_t)s * B_ + b) * NPAD + m] * __expf(pm[s] - mx);
  mxo[idx] = mx;
  rdn[idx] = 1.f / dn;
}

// ---------------- pack V (with rdn folded) into PV B-fragment layout ----------------
__global__ __launch_bounds__(256) void pack_v(
    const __hip_bfloat16* __restrict__ vb, const float* __restrict__ rdn,
    __hip_bfloat16* __restrict__ vp) {
  int idx = blockIdx.x * blockDim.x + threadIdx.x;
  if (idx >= B_ * NCHUNK * 4 * 64) return;
  int lane = idx & 63;
  int cc = (idx >> 6) & 1;
  int h = (idx >> 7) & 1;
  int t = idx >> 8;
  int c = t % NCHUNK, b = t / NCHUNK;
  int g = lane >> 4, l16 = lane & 15;
  int col = cc * 16 + l16;
  short8 o;
#pragma unroll
  for (int j = 0; j < 8; ++j) {
    int m = c * 64 + h * 32 + 16 * (j >> 2) + 4 * g + (j & 3);
    size_t mi = (size_t)b * NPAD + m;
    float vv = __bfloat162float(vb[mi * NC + col]) * rdn[mi];
    o[j] = bf16s(vv);
  }
  *(short8*)((short*)vp + (size_t)idx * 8) = o;
}

// ---------------- attention output (m-split partials): o_s[n,c] ----------------
__global__ __launch_bounds__(256) void attn_out(
    const __hip_bfloat16* __restrict__ qh, const __hip_bfloat16* __restrict__ ql,
    const __hip_bfloat16* __restrict__ kh_, const __hip_bfloat16* __restrict__ kl,
    const __hip_bfloat16* __restrict__ vp,
    const float* __restrict__ mxo,
    float* __restrict__ op, int splitm) {
  int s = blockIdx.y, b = blockIdx.z;
  int wave = threadIdx.x >> 6, lane = threadIdx.x & 63;
  int g = lane >> 4, l16 = lane & 15;
  int n16 = blockIdx.x * 64 + wave * 16;
  size_t qrow = ((size_t)b * NPAD + n16 + l16) * NC + g * 8;
  short8 bqh = *(const short8*)((const short*)qh + qrow);
  short8 bql = *(const short8*)((const short*)ql + qrow);
  const short* khb = (const short*)kh_ + (size_t)b * NPAD * NC + g * 8;
  const short* klb = (const short*)kl + (size_t)b * NPAD * NC + g * 8;
  const short* vpb = (const short*)vp + (size_t)b * NCHUNK * 4 * 64 * 8;
  const float* mxb = mxo + (size_t)b * NPAD;
  f32x4 acc0 = {0.f, 0.f, 0.f, 0.f}, acc1 = {0.f, 0.f, 0.f, 0.f};
  for (int c = s; c < NCHUNK; c += splitm) {
    int m64 = c * 64;
    short8 p0, p1;
#pragma unroll
    for (int mt = 0; mt < 4; ++mt) {
      size_t krow = (size_t)(m64 + mt * 16 + l16) * NC;
      short8 ah = *(const short8*)(khb + krow);
      short8 al = *(const short8*)(klb + krow);
      f32x4 t = __builtin_amdgcn_mfma_f32_16x16x32_bf16(ah, bqh, (f32x4){0.f, 0.f, 0.f, 0.f}, 0, 0, 0);
      t = __builtin_amdgcn_mfma_f32_16x16x32_bf16(ah, bql, t, 0, 0, 0);
      t = __builtin_amdgcn_mfma_f32_16x16x32_bf16(al, bqh, t, 0, 0, 0);
      f32x4 mxv = *(const f32x4*)(mxb + m64 + mt * 16 + 4 * g);
#pragma unroll
      for (int r = 0; r < 4; ++r) {
        short pb = bf16s(__expf(t[r] - mxv[r]));
        if (mt < 2) p0[mt * 4 + r] = pb;
        else p1[(mt - 2) * 4 + r] = pb;
      }
    }
    const short* vc = vpb + (size_t)c * 4 * 64 * 8 + (size_t)lane * 8;
    short8 v00 = *(const short8*)(vc);
    short8 v01 = *(const short8*)(vc + 512);
    short8 v10 = *(const short8*)(vc + 1024);
    short8 v11 = *(const short8*)(vc + 1536);
    acc0 = __builtin_amdgcn_mfma_f32_16x16x32_bf16(p0, v00, acc0, 0, 0, 0);
    acc1 = __builtin_amdgcn_mfma_f32_16x16x32_bf16(p0, v01, acc1, 0, 0, 0);
    acc0 = __builtin_amdgcn_mfma_f32_16x16x32_bf16(p1, v10, acc0, 0, 0, 0);
    acc1 = __builtin_amdgcn_mfma_f32_16x16x32_bf16(p1, v11, acc1, 0, 0, 0);
  }
#pragma unroll
  for (int r = 0; r < 4; ++r) {
    int n = n16 + 4 * g + r;
    if (n < N_) {
      size_t orow = (((size_t)s * B_ + b) * NPAD + n) * NC + l16;
      op[orow] = acc0[r];
      op[orow + 16] = acc1[r];
    }
  }
}

// ---------------- sum partials, scatter into zero-padded [98][98][32] ----------------
__global__ __launch_bounds__(256) void combine_o(
    const float* __restrict__ op, float* __restrict__ obz, int splitm) {
  int idx = blockIdx.x * blockDim.x + threadIdx.x;
  if (idx >= B_ * N_ * 8) return;
  int b = idx / (N_ * 8);
  int r = idx - b * (N_ * 8);
  int n = r >> 3, c4 = r & 7;
  f32x4 acc = {0.f, 0.f, 0.f, 0.f};
  for (int s = 0; s < splitm; ++s)
    acc += *(const f32x4*)(op + (((size_t)s * B_ + b) * NPAD + n) * NC + c4 * 4);
  int i = n / WO, j = n - i * WO;
  *(f32x4*)(obz + ((size_t)b * PW * PW + (i + 2) * PW + (j + 2)) * NC + c4 * 4) = acc;
}

// ---------------- fold convT weights ----------------
__global__ __launch_bounds__(256) void fold_wt(
    const float* __restrict__ wt, const float* __restrict__ bt,
    const float* __restrict__ g4, const float* __restrict__ be4,
    const float* __restrict__ m4, const float* __restrict__ v4,
    float* __restrict__ wtf, float* __restrict__ btf) {
  int idx = blockIdx.x * blockDim.x + threadIdx.x;
  if (idx < CIN * 9 * NC) {
    int oc = idx / (9 * NC);
    int r = idx - oc * (9 * NC);
    int k9 = r / NC, ic = r - k9 * NC;
    float s = g4[oc] * rsqrtf(v4[oc] + EPSV);
    wtf[idx] = wt[((size_t)ic * CIN + oc) * 9 + k9] * s;
  }
  if (idx < CIN) {
    float s = g4[idx] * rsqrtf(v4[idx] + EPSV);
    btf[idx] = (bt[idx] - m4[idx]) * s + be4[idx];
  }
}

// ---------------- convT: each thread = 1 pixel x 32 oc, branch-free via padded input ----------------
__global__ __launch_bounds__(256) void convt_k(
    const float* __restrict__ obz, const float* __restrict__ wtf,
    const float* __restrict__ btf, const float* __restrict__ x,
    float* __restrict__ out) {
  int pq = blockIdx.x * 256 + threadIdx.x;
  int ocb = blockIdx.y * 32, b = blockIdx.z;
  int p = pq / WW, q = pq - p * WW;
  const float* ozb = obz + (size_t)b * PW * PW * NC;
  float acc[32];
#pragma unroll
  for (int o = 0; o < 32; ++o) acc[o] = 0.f;
  for (int k = 0; k < 9; ++k) {
    int kh = k / 3, kw = k - kh * 3;
    const float* opx = ozb + ((size_t)(p + 2 - kh) * PW + (q + 2 - kw)) * NC;
    float4 ov[8];
#pragma unroll
    for (int i4 = 0; i4 < 8; ++i4) ov[i4] = ((const float4*)opx)[i4];
#pragma unroll
    for (int o = 0; o < 32; ++o) {
      const float4* wp = (const float4*)(wtf + ((size_t)(ocb + o) * 9 + k) * NC);
#pragma unroll
      for (int i4 = 0; i4 < 8; ++i4) {
        float4 wv = wp[i4];
        acc[o] += ov[i4].x * wv.x + ov[i4].y * wv.y + ov[i4].z * wv.z + ov[i4].w * wv.w;
      }
    }
  }
#pragma unroll
  for (int o = 0; o < 32; ++o) {
    float y = acc[o] + btf[ocb + o];
    y = y > 0.f ? y : SLOPEV * y;
    size_t oi = (((size_t)b * CIN + ocb + o) * HH + p) * WW + q;
    out[oi] = x[oi] + y;
  }
}

extern "C" void kernel_launch(void* const* d_in, const int* in_sizes, int n_in,
                              void* d_out, int out_size, void* d_ws, size_t ws_size,
                              hipStream_t stream) {
  (void)in_sizes; (void)n_in; (void)out_size;
  const float* x = (const float*)d_in[0];
  const float* w1 = (const float*)d_in[1];
  const float* b1 = (const float*)d_in[2];
  const float* g1 = (const float*)d_in[3];
  const float* be1 = (const float*)d_in[4];
  const float* m1 = (const float*)d_in[5];
  const float* v1 = (const float*)d_in[6];
  const float* w2 = (const float*)d_in[7];
  const float* b2 = (const float*)d_in[8];
  const float* g2 = (const float*)d_in[9];
  const float* be2 = (const float*)d_in[10];
  const float* m2 = (const float*)d_in[11];
  const float* v2 = (const float*)d_in[12];
  const float* w3 = (const float*)d_in[13];
  const float* b3 = (const float*)d_in[14];
  const float* g3 = (const float*)d_in[15];
  const float* be3 = (const float*)d_in[16];
  const float* m3 = (const float*)d_in[17];
  const float* v3 = (const float*)d_in[18];
  const float* wt = (const float*)d_in[19];
  const float* bt = (const float*)d_in[20];
  const float* g4 = (const float*)d_in[21];
  const float* be4 = (const float*)d_in[22];
  const float* m4 = (const float*)d_in[23];
  const float* v4 = (const float*)d_in[24];

  char* ws = (char*)d_ws;
  constexpr size_t NB = (size_t)B_ * NPAD * NC * 2;  // one bf16 buffer, bytes
  __hip_bfloat16* qh = (__hip_bfloat16*)(ws);
  __hip_bfloat16* kh = (__hip_bfloat16*)(ws + NB);
  __hip_bfloat16* vb = (__hip_bfloat16*)(ws + 2 * NB);
  __hip_bfloat16* ql = (__hip_bfloat16*)(ws + 3 * NB);
  __hip_bfloat16* kl = (__hip_bfloat16*)(ws + 4 * NB);
  __hip_bfloat16* vp = (__hip_bfloat16*)(ws + 5 * NB);
  float* mxo = (float*)(ws + 6 * NB);
  float* rdn = mxo + (size_t)B_ * NPAD;
  float* pmx = rdn + (size_t)B_ * NPAD;
  float* pdn = pmx + (size_t)SPLITN * B_ * NPAD;
  float* obz = pdn + (size_t)SPLITN * B_ * NPAD;
  float* wtf = obz + (size_t)B_ * PW * PW * NC;
  float* btf = wtf + CIN * 9 * NC;
  float* wpk1 = btf + CIN;
  float* wpk2 = wpk1 + CIN * NC * 9;
  float* wpk3 = wpk2 + CIN * NC * 9;
  float* bf1 = wpk3 + CIN * NC * 9;
  float* bf2 = bf1 + NC;
  float* bf3 = bf2 + NC;
  float* opart = bf3 + NC;
  size_t base = (size_t)((char*)opart - ws);
  constexpr size_t OBB = (size_t)B_ * NPAD * NC * 4;  // one f32 o-partial, bytes
  int splitm = 1;
  if (ws_size >= base + 8 * OBB) splitm = 8;
  else if (ws_size >= base + 4 * OBB) splitm = 4;
  else if (ws_size >= base + 2 * OBB) splitm = 2;

  // zero bf16 q/k/v buffers (pad rows) and the padded o buffer (pad ring)
  hipMemsetAsync(ws, 0, 5 * NB, stream);
  hipMemsetAsync(obz, 0, (size_t)B_ * PW * PW * NC * 4, stream);

  pack_w<<<(CIN * NC * 9 + 255) / 256, 256, 0, stream>>>(w1, b1, g1, be1, m1, v1, wpk1, bf1);
  pack_w<<<(CIN * NC * 9 + 255) / 256, 256, 0, stream>>>(w2, b2, g2, be2, m2, v2, wpk2, bf2);
  pack_w<<<(CIN * NC * 9 + 255) / 256, 256, 0, stream>>>(w3, b3, g3, be3, m3, v3, wpk3, bf3);
  fold_wt<<<(CIN * 9 * NC + 255) / 256, 256, 0, stream>>>(wt, bt, g4, be4, m4, v4, wtf, btf);

  dim3 cgrid((N_ + 255) / 256, 2, B_);
  conv_brn<<<cgrid, 256, 0, stream>>>(x, wpk1, bf1, qh, ql);
  conv_brn<<<cgrid, 256, 0, stream>>>(x, wpk2, bf2, kh, kl);
  conv_brn<<<cgrid, 256, 0, stream>>>(x, wpk3, bf3, vb, nullptr);

  attn_stats<<<dim3(NCHUNK, SPLITN, B_), 256, 0, stream>>>(qh, ql, kh, kl, pmx, pdn);
  combine_stats<<<(B_ * NPAD + 255) / 256, 256, 0, stream>>>(pmx, pdn, mxo, rdn);
  pack_v<<<(B_ * NCHUNK * 4 * 64 + 255) / 256, 256, 0, stream>>>(vb, rdn, vp);
  attn_out<<<dim3(NCHUNK, splitm, B_), 256, 0, stream>>>(qh, ql, kh, kl, vp, mxo, opart, splitm);
  combine_o<<<(B_ * N_ * 8 + 255) / 256, 256, 0, stream>>>(opart, obz, splitm);

  convt_k<<<dim3(HH * WW / 256, 2, B_), 256, 0, stream>>>(obz, wtf, btf, x, (float*)d_out);
}

// Round 4
// 379.103 us; speedup vs baseline: 1.6137x; 1.6137x over previous
//
#include <hip/hip_runtime.h>
#include <hip/hip_bf16.h>

#define B_ 2
#define CIN 64
#define HH 96
#define WW 96
#define NC 32
#define HO 94
#define WO 94
#define N_ 8836
#define NPAD 8896
#define NCHUNK 139
#define SPLITN 8
#define PW 98
#define EPSV 1e-5f
#define SLOPEV 0.01f

typedef __attribute__((ext_vector_type(8))) short short8;
typedef __attribute__((ext_vector_type(4))) float f32x4;

static_assert(NPAD == NCHUNK * 64, "pad");

union bf8u { short8 v; __hip_bfloat16 h[8]; };

// ---------------- pack conv weights: wpk[ic][9][oc] = w[oc][ic][k]*bn_scale; bfold ----------------
__global__ __launch_bounds__(256) void pack_w(
    const float* __restrict__ w, const float* __restrict__ bias,
    const float* __restrict__ g, const float* __restrict__ be,
    const float* __restrict__ m, const float* __restrict__ v,
    float* __restrict__ wpk, float* __restrict__ bfold) {
  int idx = blockIdx.x * blockDim.x + threadIdx.x;
  if (idx < CIN * 9 * NC) {
    int ic = idx / (9 * NC);
    int r = idx - ic * (9 * NC);
    int k = r / NC, oc = r - k * NC;
    float s = g[oc] * rsqrtf(v[oc] + EPSV);
    wpk[idx] = w[((size_t)oc * CIN + ic) * 9 + k] * s;
  }
  if (idx < NC) {
    float s = g[idx] * rsqrtf(v[idx] + EPSV);
    bfold[idx] = (bias[idx] - m[idx]) * s + be[idx];
  }
}

// ---------------- conv branches: 64-thr blocks, each thread = 1 pixel x 8 oc ----------------
__global__ __launch_bounds__(64) void conv_brn(
    const float* __restrict__ x, const float* __restrict__ wpk,
    const float* __restrict__ bfold,
    __hip_bfloat16* __restrict__ ohi, __hip_bfloat16* __restrict__ olo) {
  int n = blockIdx.x * 64 + threadIdx.x;
  int ocb = blockIdx.y * 8, b = blockIdx.z;
  if (n >= N_) return;
  int oh = n / WO, ow = n - oh * WO;
  const float* xb = x + (size_t)b * CIN * HH * WW + oh * WW + ow;
  float acc[8];
#pragma unroll
  for (int o = 0; o < 8; ++o) acc[o] = 0.f;
  for (int ic = 0; ic < CIN; ++ic) {
    const float* xr = xb + ic * HH * WW;
    float xv[9];
#pragma unroll
    for (int r = 0; r < 3; ++r)
#pragma unroll
      for (int cc = 0; cc < 3; ++cc) xv[r * 3 + cc] = xr[r * WW + cc];
    const float* wb = wpk + (size_t)ic * 9 * NC + ocb;
#pragma unroll
    for (int k = 0; k < 9; ++k) {
      const float* wk = wb + k * NC;
#pragma unroll
      for (int o = 0; o < 8; ++o) acc[o] = fmaf(xv[k], wk[o], acc[o]);
    }
  }
  size_t orow = ((size_t)b * NPAD + n) * NC + ocb;
  bf8u H, L;
#pragma unroll
  for (int o = 0; o < 8; ++o) {
    float y = acc[o] + bfold[ocb + o];
    y = y > 0.f ? y : SLOPEV * y;
    H.h[o] = __float2bfloat16(y);
    L.h[o] = __float2bfloat16(y - __bfloat162float(H.h[o]));
  }
  *(short8*)&ohi[orow] = H.v;
  if (olo) *(short8*)&olo[orow] = L.v;
}

// ---------------- stats pass: per-lane online (mx, dn) over an n-slice ----------------
__global__ __launch_bounds__(256) void attn_stats(
    const __hip_bfloat16* __restrict__ qh, const __hip_bfloat16* __restrict__ ql,
    const __hip_bfloat16* __restrict__ kh_, const __hip_bfloat16* __restrict__ kl,
    float* __restrict__ pmx, float* __restrict__ pdn) {
  int s = blockIdx.y, b = blockIdx.z;
  int wave = threadIdx.x >> 6, lane = threadIdx.x & 63;
  int g = lane >> 4, l16 = lane & 15;
  int m16 = blockIdx.x * 64 + wave * 16;
  size_t arow = ((size_t)b * NPAD + m16 + l16) * NC + g * 8;
  short8 akh = *(const short8*)((const short*)kh_ + arow);
  short8 akl = *(const short8*)((const short*)kl + arow);
  const short* qhb = (const short*)qh + (size_t)b * NPAD * NC + g * 8;
  const short* qlb = (const short*)ql + (size_t)b * NPAD * NC + g * 8;
  float mx[4] = {-1e30f, -1e30f, -1e30f, -1e30f};
  float dn[4] = {0.f, 0.f, 0.f, 0.f};
  for (int c = s; c < NCHUNK; c += SPLITN) {
    f32x4 T[4];
#pragma unroll
    for (int nt = 0; nt < 4; ++nt) {
      int n = c * 64 + nt * 16 + l16;
      short8 bh = *(const short8*)(qhb + (size_t)n * NC);
      short8 bl = *(const short8*)(qlb + (size_t)n * NC);
      f32x4 t = __builtin_amdgcn_mfma_f32_16x16x32_bf16(akh, bh, (f32x4){0.f, 0.f, 0.f, 0.f}, 0, 0, 0);
      t = __builtin_amdgcn_mfma_f32_16x16x32_bf16(akh, bl, t, 0, 0, 0);
      t = __builtin_amdgcn_mfma_f32_16x16x32_bf16(akl, bh, t, 0, 0, 0);
      T[nt] = t;
    }
    if (c == NCHUNK - 1) {
#pragma unroll
      for (int nt = 0; nt < 4; ++nt)
        if (c * 64 + nt * 16 + l16 >= N_)
          T[nt] = (f32x4){-1e30f, -1e30f, -1e30f, -1e30f};
    }
#pragma unroll
    for (int r = 0; r < 4; ++r) {
      float cm = fmaxf(fmaxf(T[0][r], T[1][r]), fmaxf(T[2][r], T[3][r]));
      float nm = fmaxf(mx[r], cm);
      float cs = __expf(T[0][r] - nm) + __expf(T[1][r] - nm) +
                 __expf(T[2][r] - nm) + __expf(T[3][r] - nm);
      dn[r] = dn[r] * __expf(mx[r] - nm) + cs;
      mx[r] = nm;
    }
  }
#pragma unroll
  for (int r = 0; r < 4; ++r) {
#pragma unroll
    for (int off = 1; off < 16; off <<= 1) {
      float omx = __shfl_xor(mx[r], off);
      float odn = __shfl_xor(dn[r], off);
      float nm = fmaxf(mx[r], omx);
      dn[r] = dn[r] * __expf(mx[r] - nm) + odn * __expf(omx - nm);
      mx[r] = nm;
    }
    if (l16 == 0) {
      size_t mi = ((size_t)s * B_ + b) * NPAD + m16 + 4 * g + r;
      pmx[mi] = mx[r];
      pdn[mi] = dn[r];
    }
  }
}

// ---------------- merge partials into fac = exp(-mx)/dn ----------------
__global__ __launch_bounds__(256) void combine_stats(
    const float* __restrict__ pmx, const float* __restrict__ pdn,
    float* __restrict__ fac) {
  int idx = blockIdx.x * blockDim.x + threadIdx.x;
  if (idx >= B_ * NPAD) return;
  int b = idx / NPAD, m = idx - b * NPAD;
  float pm[SPLITN];
  float mx = -1e30f;
#pragma unroll
  for (int s = 0; s < SPLITN; ++s) {
    pm[s] = pmx[((size_t)s * B_ + b) * NPAD + m];
    mx = fmaxf(mx, pm[s]);
  }
  float dn = 0.f;
#pragma unroll
  for (int s = 0; s < SPLITN; ++s)
    dn += pdn[((size_t)s * B_ + b) * NPAD + m] * __expf(pm[s] - mx);
  fac[idx] = __expf(-mx) / dn;
}

// ---------------- pack V (with fac folded) into PV B-fragment layout ----------------
__global__ __launch_bounds__(256) void pack_v(
    const __hip_bfloat16* __restrict__ vb, const float* __restrict__ fac,
    __hip_bfloat16* __restrict__ vp) {
  int idx = blockIdx.x * blockDim.x + threadIdx.x;
  if (idx >= B_ * NCHUNK * 4 * 64) return;
  int lane = idx & 63;
  int cc = (idx >> 6) & 1;
  int h = (idx >> 7) & 1;
  int t = idx >> 8;
  int c = t % NCHUNK, b = t / NCHUNK;
  int g = lane >> 4, l16 = lane & 15;
  int col = cc * 16 + l16;
  bf8u o;
#pragma unroll
  for (int j = 0; j < 8; ++j) {
    int m = c * 64 + h * 32 + 16 * (j >> 2) + 4 * g + (j & 3);
    size_t mi = (size_t)b * NPAD + m;
    float vv = __bfloat162float(vb[mi * NC + col]) * fac[mi];
    o.h[j] = __float2bfloat16(vv);
  }
  *(short8*)((short*)vp + (size_t)idx * 8) = o.v;
}

// ---------------- attention output (m-split partials): P = exp(S), V' has fac folded ----------------
__global__ __launch_bounds__(256) void attn_out(
    const __hip_bfloat16* __restrict__ qh, const __hip_bfloat16* __restrict__ ql,
    const __hip_bfloat16* __restrict__ kh_, const __hip_bfloat16* __restrict__ kl,
    const __hip_bfloat16* __restrict__ vp,
    float* __restrict__ op, int splitm) {
  int s = blockIdx.y, b = blockIdx.z;
  int wave = threadIdx.x >> 6, lane = threadIdx.x & 63;
  int g = lane >> 4, l16 = lane & 15;
  int n16 = blockIdx.x * 64 + wave * 16;
  size_t qrow = ((size_t)b * NPAD + n16 + l16) * NC + g * 8;
  short8 bqh = *(const short8*)((const short*)qh + qrow);
  short8 bql = *(const short8*)((const short*)ql + qrow);
  const short* khb = (const short*)kh_ + (size_t)b * NPAD * NC + g * 8;
  const short* klb = (const short*)kl + (size_t)b * NPAD * NC + g * 8;
  const short* vpb = (const short*)vp + (size_t)b * NCHUNK * 4 * 64 * 8;
  f32x4 acc0 = {0.f, 0.f, 0.f, 0.f}, acc1 = {0.f, 0.f, 0.f, 0.f};
  for (int c = s; c < NCHUNK; c += splitm) {
    int m64 = c * 64;
    bf8u P0, P1;
#pragma unroll
    for (int mt = 0; mt < 4; ++mt) {
      size_t krow = (size_t)(m64 + mt * 16 + l16) * NC;
      short8 ah = *(const short8*)(khb + krow);
      short8 al = *(const short8*)(klb + krow);
      f32x4 t = __builtin_amdgcn_mfma_f32_16x16x32_bf16(ah, bqh, (f32x4){0.f, 0.f, 0.f, 0.f}, 0, 0, 0);
      t = __builtin_amdgcn_mfma_f32_16x16x32_bf16(ah, bql, t, 0, 0, 0);
      t = __builtin_amdgcn_mfma_f32_16x16x32_bf16(al, bqh, t, 0, 0, 0);
#pragma unroll
      for (int r = 0; r < 4; ++r) {
        __hip_bfloat16 pb = __float2bfloat16(__expf(t[r]));
        if (mt < 2) P0.h[mt * 4 + r] = pb;
        else P1.h[(mt - 2) * 4 + r] = pb;
      }
    }
    const short* vc = vpb + (size_t)c * 4 * 64 * 8 + (size_t)lane * 8;
    short8 v00 = *(const short8*)(vc);
    short8 v01 = *(const short8*)(vc + 512);
    short8 v10 = *(const short8*)(vc + 1024);
    short8 v11 = *(const short8*)(vc + 1536);
    acc0 = __builtin_amdgcn_mfma_f32_16x16x32_bf16(P0.v, v00, acc0, 0, 0, 0);
    acc1 = __builtin_amdgcn_mfma_f32_16x16x32_bf16(P0.v, v01, acc1, 0, 0, 0);
    acc0 = __builtin_amdgcn_mfma_f32_16x16x32_bf16(P1.v, v10, acc0, 0, 0, 0);
    acc1 = __builtin_amdgcn_mfma_f32_16x16x32_bf16(P1.v, v11, acc1, 0, 0, 0);
  }
#pragma unroll
  for (int r = 0; r < 4; ++r) {
    int n = n16 + 4 * g + r;
    if (n < N_) {
      size_t orow = (((size_t)s * B_ + b) * NPAD + n) * NC + l16;
      op[orow] = acc0[r];
      op[orow + 16] = acc1[r];
    }
  }
}

// ---------------- sum partials, scatter into zero-padded [98][98][32] ----------------
__global__ __launch_bounds__(256) void combine_o(
    const float* __restrict__ op, float* __restrict__ obz, int splitm) {
  int idx = blockIdx.x * blockDim.x + threadIdx.x;
  if (idx >= B_ * N_ * 8) return;
  int b = idx / (N_ * 8);
  int r = idx - b * (N_ * 8);
  int n = r >> 3, c4 = r & 7;
  f32x4 acc = {0.f, 0.f, 0.f, 0.f};
  for (int s = 0; s < splitm; ++s)
    acc += *(const f32x4*)(op + (((size_t)s * B_ + b) * NPAD + n) * NC + c4 * 4);
  int i = n / WO, j = n - i * WO;
  *(f32x4*)(obz + ((size_t)b * PW * PW + (i + 2) * PW + (j + 2)) * NC + c4 * 4) = acc;
}

// ---------------- fold convT weights: wtf[oc][k][ic] ----------------
__global__ __launch_bounds__(256) void fold_wt(
    const float* __restrict__ wt, const float* __restrict__ bt,
    const float* __restrict__ g4, const float* __restrict__ be4,
    const float* __restrict__ m4, const float* __restrict__ v4,
    float* __restrict__ wtf, float* __restrict__ btf) {
  int idx = blockIdx.x * blockDim.x + threadIdx.x;
  if (idx < CIN * 9 * NC) {
    int oc = idx / (9 * NC);
    int r = idx - oc * (9 * NC);
    int k9 = r / NC, ic = r - k9 * NC;
    float s = g4[oc] * rsqrtf(v4[oc] + EPSV);
    wtf[idx] = wt[((size_t)ic * CIN + oc) * 9 + k9] * s;
  }
  if (idx < CIN) {
    float s = g4[idx] * rsqrtf(v4[idx] + EPSV);
    btf[idx] = (bt[idx] - m4[idx]) * s + be4[idx];
  }
}

// ---------------- convT: 64-thr blocks, each thread = 1 pixel x 8 oc ----------------
__global__ __launch_bounds__(64) void convt_k(
    const float* __restrict__ obz, const float* __restrict__ wtf,
    const float* __restrict__ btf, const float* __restrict__ x,
    float* __restrict__ out) {
  int pq = blockIdx.x * 64 + threadIdx.x;
  int ocb = blockIdx.y * 8, b = blockIdx.z;
  int p = pq / WW, q = pq - p * WW;
  const float* ozb = obz + (size_t)b * PW * PW * NC;
  float acc[8];
#pragma unroll
  for (int o = 0; o < 8; ++o) acc[o] = 0.f;
#pragma unroll
  for (int k = 0; k < 9; ++k) {
    int kh = k / 3, kw = k - kh * 3;
    const float* opx = ozb + ((size_t)(p + 2 - kh) * PW + (q + 2 - kw)) * NC;
    float4 ov[8];
#pragma unroll
    for (int i4 = 0; i4 < 8; ++i4) ov[i4] = ((const float4*)opx)[i4];
#pragma unroll
    for (int o = 0; o < 8; ++o) {
      const float4* wp = (const float4*)(wtf + ((size_t)(ocb + o) * 9 + k) * NC);
#pragma unroll
      for (int i4 = 0; i4 < 8; ++i4) {
        float4 wv = wp[i4];
        acc[o] += ov[i4].x * wv.x + ov[i4].y * wv.y + ov[i4].z * wv.z + ov[i4].w * wv.w;
      }
    }
  }
#pragma unroll
  for (int o = 0; o < 8; ++o) {
    float y = acc[o] + btf[ocb + o];
    y = y > 0.f ? y : SLOPEV * y;
    size_t oi = (((size_t)b * CIN + ocb + o) * HH + p) * WW + q;
    out[oi] = x[oi] + y;
  }
}

extern "C" void kernel_launch(void* const* d_in, const int* in_sizes, int n_in,
                              void* d_out, int out_size, void* d_ws, size_t ws_size,
                              hipStream_t stream) {
  (void)in_sizes; (void)n_in; (void)out_size;
  const float* x = (const float*)d_in[0];
  const float* w1 = (const float*)d_in[1];
  const float* b1 = (const float*)d_in[2];
  const float* g1 = (const float*)d_in[3];
  const float* be1 = (const float*)d_in[4];
  const float* m1 = (const float*)d_in[5];
  const float* v1 = (const float*)d_in[6];
  const float* w2 = (const float*)d_in[7];
  const float* b2 = (const float*)d_in[8];
  const float* g2 = (const float*)d_in[9];
  const float* be2 = (const float*)d_in[10];
  const float* m2 = (const float*)d_in[11];
  const float* v2 = (const float*)d_in[12];
  const float* w3 = (const float*)d_in[13];
  const float* b3 = (const float*)d_in[14];
  const float* g3 = (const float*)d_in[15];
  const float* be3 = (const float*)d_in[16];
  const float* m3 = (const float*)d_in[17];
  const float* v3 = (const float*)d_in[18];
  const float* wt = (const float*)d_in[19];
  const float* bt = (const float*)d_in[20];
  const float* g4 = (const float*)d_in[21];
  const float* be4 = (const float*)d_in[22];
  const float* m4 = (const float*)d_in[23];
  const float* v4 = (const float*)d_in[24];

  char* ws = (char*)d_ws;
  constexpr size_t NB = (size_t)B_ * NPAD * NC * 2;  // one bf16 buffer, bytes
  __hip_bfloat16* qh = (__hip_bfloat16*)(ws);
  __hip_bfloat16* kh = (__hip_bfloat16*)(ws + NB);
  __hip_bfloat16* vb = (__hip_bfloat16*)(ws + 2 * NB);
  __hip_bfloat16* ql = (__hip_bfloat16*)(ws + 3 * NB);
  __hip_bfloat16* kl = (__hip_bfloat16*)(ws + 4 * NB);
  __hip_bfloat16* vp = (__hip_bfloat16*)(ws + 5 * NB);
  float* fac = (float*)(ws + 6 * NB);
  float* pmx = fac + (size_t)B_ * NPAD;
  float* pdn = pmx + (size_t)SPLITN * B_ * NPAD;
  float* obz = pdn + (size_t)SPLITN * B_ * NPAD;
  float* wtf = obz + (size_t)B_ * PW * PW * NC;
  float* btf = wtf + CIN * 9 * NC;
  float* wpk1 = btf + CIN;
  float* wpk2 = wpk1 + CIN * NC * 9;
  float* wpk3 = wpk2 + CIN * NC * 9;
  float* bf1 = wpk3 + CIN * NC * 9;
  float* bf2 = bf1 + NC;
  float* bf3 = bf2 + NC;
  float* opart = bf3 + NC;
  size_t base = (size_t)((char*)opart - ws);
  constexpr size_t OBB = (size_t)B_ * NPAD * NC * 4;  // one f32 o-partial, bytes
  int splitm = 1;
  if (ws_size >= base + 8 * OBB) splitm = 8;
  else if (ws_size >= base + 4 * OBB) splitm = 4;
  else if (ws_size >= base + 2 * OBB) splitm = 2;

  // zero bf16 q/k/v buffers (pad rows) and the padded o buffer (pad ring)
  hipMemsetAsync(ws, 0, 5 * NB, stream);
  hipMemsetAsync(obz, 0, (size_t)B_ * PW * PW * NC * 4, stream);

  pack_w<<<(CIN * NC * 9 + 255) / 256, 256, 0, stream>>>(w1, b1, g1, be1, m1, v1, wpk1, bf1);
  pack_w<<<(CIN * NC * 9 + 255) / 256, 256, 0, stream>>>(w2, b2, g2, be2, m2, v2, wpk2, bf2);
  pack_w<<<(CIN * NC * 9 + 255) / 256, 256, 0, stream>>>(w3, b3, g3, be3, m3, v3, wpk3, bf3);
  fold_wt<<<(CIN * 9 * NC + 255) / 256, 256, 0, stream>>>(wt, bt, g4, be4, m4, v4, wtf, btf);

  dim3 cgrid(NCHUNK, NC / 8, B_);
  conv_brn<<<cgrid, 64, 0, stream>>>(x, wpk1, bf1, qh, ql);
  conv_brn<<<cgrid, 64, 0, stream>>>(x, wpk2, bf2, kh, kl);
  conv_brn<<<cgrid, 64, 0, stream>>>(x, wpk3, bf3, vb, nullptr);

  attn_stats<<<dim3(NCHUNK, SPLITN, B_), 256, 0, stream>>>(qh, ql, kh, kl, pmx, pdn);
  combine_stats<<<(B_ * NPAD + 255) / 256, 256, 0, stream>>>(pmx, pdn, fac);
  pack_v<<<(B_ * NCHUNK * 4 * 64 + 255) / 256, 256, 0, stream>>>(vb, fac, vp);
  attn_out<<<dim3(NCHUNK, splitm, B_), 256, 0, stream>>>(qh, ql, kh, kl, vp, opart, splitm);
  combine_o<<<(B_ * N_ * 8 + 255) / 256, 256, 0, stream>>>(opart, obz, splitm);

  convt_k<<<dim3(HH * WW / 64, CIN / 8, B_), 64, 0, stream>>>(obz, wtf, btf, x, (float*)d_out);
}